// Round 9
// baseline (711.656 us; speedup 1.0000x reference)
//
#include <hip/hip_runtime.h>
#include <hip/hip_fp16.h>

// TemporalEMA: out = ALPHA * bilinear_warp(prev, mv) + (1-ALPHA) * cur
// R9 = R8 + x-coarsening (2 px/thread) to halve streaming VMEM instruction
// count (42 -> ~21 VMEM instrs per pixel was the R8 limiter: VALU 10.8%,
// BW 37%, neither pipe saturated). cur/out/mv move as dwordx2; gathers stay
// 2x64B lines per pixel from the f16 pixel-major ws (L3-resident, 265 MB).

#define ALPHA 0.85f

constexpr int Bc = 4;
constexpr int Cc = 16;
constexpr int Hc = 1080;
constexpr int Wc = 1920;
constexpr size_t PLANE = (size_t)Hc * Wc;
constexpr size_t WS_NEED = (size_t)Bc * PLANE * Cc * sizeof(__half);  // 265 MB

constexpr int VPT = 2;                  // pixels per thread along x
constexpr int TW = 64 * VPT;            // 128 px per wave
constexpr int TH = 4;
constexpr int NX = Wc / TW;             // 15
constexpr int NY = Hc / TH;             // 270
constexpr int NBLK = Bc * NY * NX;      // 16200
constexpr int NXCD = 8;
constexpr int CHUNK = NBLK / NXCD;      // 2025 (divisible -> bijective)

constexpr int RBLK_PER_B = (int)(PLANE / 512);  // 4050 (2 px/thread repack)

typedef float f2 __attribute__((ext_vector_type(2)));
typedef unsigned int u4 __attribute__((ext_vector_type(4)));

// ---------------- kernel 1: repack prev -> [B,H,W,C16] f16, 2 px/thread ----------------
__global__ __launch_bounds__(256) void TemporalEMA_repack_kernel(
    const float* __restrict__ prev, __half* __restrict__ ws)
{
    const int b  = blockIdx.x / RBLK_PER_B;
    const int wb = blockIdx.x % RBLK_PER_B;
    const size_t pix = (size_t)wb * 512 + threadIdx.x * 2;   // within plane

    const float* src = prev + (size_t)b * Cc * PLANE + pix;
    union { __half h[32]; u4 q[4]; } u;   // [c][px] interleave target: px-major
    #pragma unroll
    for (int c = 0; c < Cc; ++c) {
        const f2 v = *(const f2*)(src + (size_t)c * PLANE);
        u.h[c]      = __float2half(v.x);   // pixel 0, channel c
        u.h[16 + c] = __float2half(v.y);   // pixel 1, channel c
    }

    u4* dst = (u4*)(ws + ((size_t)b * PLANE + pix) * Cc);
    #pragma unroll
    for (int j = 0; j < 4; ++j)
        __builtin_nontemporal_store(u.q[j], &dst[j]);
}

// ---------------- kernel 2: gather from packed f16 + EMA blend, 2 px/thread ----------------
__global__ __launch_bounds__(256) void TemporalEMA_73194832658797_kernel(
    const float* __restrict__ cur,
    const __half* __restrict__ wsp,
    const float* __restrict__ mv,
    float* __restrict__ out)
{
    const int bid  = blockIdx.x;
    const int work = (bid % NXCD) * CHUNK + bid / NXCD;   // chunked XCD swizzle

    const int tx  = work % NX;
    const int rem = work / NX;
    const int ty  = rem % NY;
    const int b   = rem / NY;

    const int lw = threadIdx.x & 63;
    const int lh = threadIdx.x >> 6;
    const int wbase = tx * TW + lw * VPT;    // pixels wbase, wbase+1
    const int h  = ty * TH + lh;

    const size_t pix0 = (size_t)h * Wc + wbase;

    // mv as f2 (consecutive x)
    const f2 mvx2 = *(const f2*)(mv + ((size_t)b * 2 + 0) * PLANE + pix0);
    const f2 mvy2 = *(const f2*)(mv + ((size_t)b * 2 + 1) * PLANE + pix0);

    const float sxk = (float)(Wc - 1) / (float)Wc;
    const float syk = (float)(Hc - 1) / (float)Hc;

    float warped[VPT][Cc];

    #pragma unroll
    for (int p = 0; p < VPT; ++p) {
        const int w = wbase + p;
        const float mvx = (p == 0) ? mvx2.x : mvx2.y;
        const float mvy = (p == 0) ? mvy2.x : mvy2.y;
        float px = fminf(fmaxf((float)w - mvx * sxk, 0.0f), (float)(Wc - 1));
        float py = fminf(fmaxf((float)h - mvy * syk, 0.0f), (float)(Hc - 1));
        const int x0 = min((int)floorf(px), Wc - 2);   // weights absorb border
        const int y0 = min((int)floorf(py), Hc - 2);
        const float wx = px - (float)x0;
        const float wy = py - (float)y0;
        const float w00 = (1.0f - wx) * (1.0f - wy);
        const float w01 = wx * (1.0f - wy);
        const float w10 = (1.0f - wx) * wy;
        const float w11 = wx * wy;

        const size_t p00 = ((size_t)b * PLANE + (size_t)y0 * Wc + x0) * Cc;
        const u4* g0 = (const u4*)(wsp + p00);                    // v00|v01
        const u4* g1 = (const u4*)(wsp + p00 + (size_t)Wc * Cc);  // v10|v11

        u4 q[4], r[4];
        #pragma unroll
        for (int j = 0; j < 4; ++j) { q[j] = g0[j]; r[j] = g1[j]; }
        const __half* t0 = (const __half*)&q[0];   // v00 ch0..15 | v01 ch0..15
        const __half* t1 = (const __half*)&r[0];   // v10 ch0..15 | v11 ch0..15

        #pragma unroll
        for (int c = 0; c < Cc; ++c) {
            warped[p][c] = __half2float(t0[c])      * w00
                         + __half2float(t0[Cc + c]) * w01
                         + __half2float(t1[c])      * w10
                         + __half2float(t1[Cc + c]) * w11;
        }
    }

    const size_t cb0 = (size_t)b * Cc * PLANE + pix0;
    #pragma unroll
    for (int c = 0; c < Cc; ++c) {
        const f2 cu = *(const f2*)(cur + cb0 + (size_t)c * PLANE);
        f2 o;
        o.x = ALPHA * warped[0][c] + (1.0f - ALPHA) * cu.x;
        o.y = ALPHA * warped[1][c] + (1.0f - ALPHA) * cu.y;
        __builtin_nontemporal_store(o, (f2*)(out + cb0 + (size_t)c * PLANE));
    }
}

// ---------------- fallback: R4 direct f32 gather (if ws too small) ----------------
constexpr int FNX = Wc / 64;          // 30
constexpr int FNY = Hc / 4;           // 270
constexpr int FNBLK = Bc * FNY * FNX; // 32400
constexpr int FCHUNK = FNBLK / NXCD;

__global__ __launch_bounds__(256) void TemporalEMA_fallback_kernel(
    const float* __restrict__ cur,
    const float* __restrict__ prev,
    const float* __restrict__ mv,
    float* __restrict__ out)
{
    const int bid  = blockIdx.x;
    const int work = (bid % NXCD) * FCHUNK + bid / NXCD;
    const int tx  = work % FNX;
    const int rem = work / FNX;
    const int ty  = rem % FNY;
    const int b   = rem / FNY;
    const int lw = threadIdx.x & 63;
    const int lh = threadIdx.x >> 6;
    const int w  = tx * 64 + lw;
    const int h  = ty * 4 + lh;
    const size_t pix = (size_t)h * Wc + w;

    const float mvx = mv[((size_t)b * 2 + 0) * PLANE + pix];
    const float mvy = mv[((size_t)b * 2 + 1) * PLANE + pix];
    const float sxk = (float)(Wc - 1) / (float)Wc;
    const float syk = (float)(Hc - 1) / (float)Hc;
    float px = fminf(fmaxf((float)w - mvx * sxk, 0.0f), (float)(Wc - 1));
    float py = fminf(fmaxf((float)h - mvy * syk, 0.0f), (float)(Hc - 1));
    const int x0 = min((int)floorf(px), Wc - 2);
    const int y0 = min((int)floorf(py), Hc - 2);
    const float wx = px - (float)x0;
    const float wy = py - (float)y0;
    const float w00 = (1.0f - wx) * (1.0f - wy);
    const float w01 = wx * (1.0f - wy);
    const float w10 = (1.0f - wx) * wy;
    const float w11 = wx * wy;
    const size_t o0 = (size_t)y0 * Wc + x0;
    const size_t o1 = o0 + Wc;
    const size_t base_b = (size_t)b * Cc * PLANE;

    #pragma unroll
    for (int cg = 0; cg < Cc; cg += 4) {
        f2 p0[4], p1[4];
        float cu[4];
        #pragma unroll
        for (int j = 0; j < 4; ++j) {
            const size_t cb = base_b + (size_t)(cg + j) * PLANE;
            p0[j] = *(const f2*)(prev + cb + o0);
            p1[j] = *(const f2*)(prev + cb + o1);
            cu[j] = cur[cb + pix];
        }
        #pragma unroll
        for (int j = 0; j < 4; ++j) {
            const size_t cb = base_b + (size_t)(cg + j) * PLANE;
            const float warped = p0[j].x * w00 + p0[j].y * w01
                               + p1[j].x * w10 + p1[j].y * w11;
            out[cb + pix] = ALPHA * warped + (1.0f - ALPHA) * cu[j];
        }
    }
}

extern "C" void kernel_launch(void* const* d_in, const int* in_sizes, int n_in,
                              void* d_out, int out_size, void* d_ws, size_t ws_size,
                              hipStream_t stream) {
    const float* cur  = (const float*)d_in[0];
    const float* prev = (const float*)d_in[1];
    const float* mv   = (const float*)d_in[2];
    float* out = (float*)d_out;

    if (ws_size >= WS_NEED) {
        __half* ws = (__half*)d_ws;
        TemporalEMA_repack_kernel<<<Bc * RBLK_PER_B, 256, 0, stream>>>(prev, ws);
        TemporalEMA_73194832658797_kernel<<<NBLK, 256, 0, stream>>>(cur, ws, mv, out);
    } else {
        TemporalEMA_fallback_kernel<<<FNBLK, 256, 0, stream>>>(cur, prev, mv, out);
    }
}

// Round 10
// 561.612 us; speedup vs baseline: 1.2672x; 1.2672x over previous
//
#include <hip/hip_runtime.h>
#include <hip/hip_fp16.h>

// TemporalEMA: out = ALPHA * bilinear_warp(prev, mv) + (1-ALPHA) * cur
// R10 = R8 (1 px/thread, pixel-major f16 ws) + register-pressure fix:
// __launch_bounds__(256,4) caps VGPR at 128 (vs 36 in R8, which forced the
// compiler to serialize cur-loads into the blend loop -> ~16 exposed vmcnt
// round trips/thread). Source order: 8 tap loads -> 16 cur loads -> consume.
// R9's x-coarsening regressed (VGPR pressure serialized the 2 gather chains);
// reverted.

#define ALPHA 0.85f

constexpr int Bc = 4;
constexpr int Cc = 16;
constexpr int Hc = 1080;
constexpr int Wc = 1920;
constexpr size_t PLANE = (size_t)Hc * Wc;
constexpr size_t WS_NEED = (size_t)Bc * PLANE * Cc * sizeof(__half);  // 265 MB

constexpr int TW = 64;
constexpr int TH = 4;
constexpr int NX = Wc / TW;          // 30
constexpr int NY = Hc / TH;          // 270
constexpr int NBLK = Bc * NY * NX;   // 32400
constexpr int NXCD = 8;
constexpr int CHUNK = NBLK / NXCD;   // 4050

constexpr int BLK_PER_B = (int)(PLANE / 256);  // 8100 (exact)

typedef float f2 __attribute__((ext_vector_type(2)));
typedef unsigned int u4 __attribute__((ext_vector_type(4)));

// ---------------- kernel 1: repack prev -> [B,H,W,C16] f16 (R8 form) ----------------
__global__ __launch_bounds__(256) void TemporalEMA_repack_kernel(
    const float* __restrict__ prev, __half* __restrict__ ws)
{
    const int b  = blockIdx.x / BLK_PER_B;
    const int wb = blockIdx.x % BLK_PER_B;
    const size_t pix = (size_t)wb * 256 + threadIdx.x;   // within plane

    const float* src = prev + (size_t)b * Cc * PLANE + pix;
    union { __half h[16]; u4 q[2]; } u;
    #pragma unroll
    for (int c = 0; c < Cc; ++c)
        u.h[c] = __float2half(src[(size_t)c * PLANE]);

    u4* dst = (u4*)(ws + ((size_t)b * PLANE + pix) * Cc);
    __builtin_nontemporal_store(u.q[0], &dst[0]);
    __builtin_nontemporal_store(u.q[1], &dst[1]);
}

// ---------------- kernel 2: gather + blend, high-MLP version ----------------
__global__ __launch_bounds__(256, 4) void TemporalEMA_73194832658797_kernel(
    const float* __restrict__ cur,
    const __half* __restrict__ wsp,
    const float* __restrict__ mv,
    float* __restrict__ out)
{
    const int bid  = blockIdx.x;
    const int work = (bid % NXCD) * CHUNK + bid / NXCD;   // chunked XCD swizzle

    const int tx  = work % NX;
    const int rem = work / NX;
    const int ty  = rem % NY;
    const int b   = rem / NY;

    const int lw = threadIdx.x & 63;
    const int lh = threadIdx.x >> 6;
    const int w  = tx * TW + lw;
    const int h  = ty * TH + lh;

    const size_t pix = (size_t)h * Wc + w;

    const float mvx = __builtin_nontemporal_load(&mv[((size_t)b * 2 + 0) * PLANE + pix]);
    const float mvy = __builtin_nontemporal_load(&mv[((size_t)b * 2 + 1) * PLANE + pix]);

    const float sxk = (float)(Wc - 1) / (float)Wc;
    const float syk = (float)(Hc - 1) / (float)Hc;
    float px = fminf(fmaxf((float)w - mvx * sxk, 0.0f), (float)(Wc - 1));
    float py = fminf(fmaxf((float)h - mvy * syk, 0.0f), (float)(Hc - 1));

    const int x0 = min((int)floorf(px), Wc - 2);   // weights absorb border clamp
    const int y0 = min((int)floorf(py), Hc - 2);
    const float wx = px - (float)x0;
    const float wy = py - (float)y0;

    const float w00 = (1.0f - wx) * (1.0f - wy);
    const float w01 = wx * (1.0f - wy);
    const float w10 = (1.0f - wx) * wy;
    const float w11 = wx * wy;

    // ---- issue ALL loads up front: 8 tap u4s, then 16 cur dwords ----
    const size_t p00 = ((size_t)b * PLANE + (size_t)y0 * Wc + x0) * Cc;
    const u4* g0 = (const u4*)(wsp + p00);                    // v00|v01
    const u4* g1 = (const u4*)(wsp + p00 + (size_t)Wc * Cc);  // v10|v11

    u4 q[4], r[4];
    #pragma unroll
    for (int j = 0; j < 4; ++j) q[j] = g0[j];
    #pragma unroll
    for (int j = 0; j < 4; ++j) r[j] = g1[j];

    const size_t cb0 = (size_t)b * Cc * PLANE + pix;
    float cu[Cc];
    #pragma unroll
    for (int c = 0; c < Cc; ++c)
        cu[c] = __builtin_nontemporal_load(&cur[cb0 + (size_t)c * PLANE]);

    // ---- consume ----
    const __half* t0 = (const __half*)&q[0];   // [32]: v00 ch0..15 | v01 ch0..15
    const __half* t1 = (const __half*)&r[0];   // [32]: v10 ch0..15 | v11 ch0..15

    #pragma unroll
    for (int c = 0; c < Cc; ++c) {
        const float v00 = __half2float(t0[c]);
        const float v01 = __half2float(t0[Cc + c]);
        const float v10 = __half2float(t1[c]);
        const float v11 = __half2float(t1[Cc + c]);
        const float warped = v00 * w00 + v01 * w01 + v10 * w10 + v11 * w11;
        __builtin_nontemporal_store(ALPHA * warped + (1.0f - ALPHA) * cu[c],
                                    &out[cb0 + (size_t)c * PLANE]);
    }
}

// ---------------- fallback: R4 direct f32 gather (if ws too small) ----------------
__global__ __launch_bounds__(256) void TemporalEMA_fallback_kernel(
    const float* __restrict__ cur,
    const float* __restrict__ prev,
    const float* __restrict__ mv,
    float* __restrict__ out)
{
    const int bid  = blockIdx.x;
    const int work = (bid % NXCD) * CHUNK + bid / NXCD;
    const int tx  = work % NX;
    const int rem = work / NX;
    const int ty  = rem % NY;
    const int b   = rem / NY;
    const int lw = threadIdx.x & 63;
    const int lh = threadIdx.x >> 6;
    const int w  = tx * TW + lw;
    const int h  = ty * TH + lh;
    const size_t pix = (size_t)h * Wc + w;

    const float mvx = mv[((size_t)b * 2 + 0) * PLANE + pix];
    const float mvy = mv[((size_t)b * 2 + 1) * PLANE + pix];
    const float sxk = (float)(Wc - 1) / (float)Wc;
    const float syk = (float)(Hc - 1) / (float)Hc;
    float px = fminf(fmaxf((float)w - mvx * sxk, 0.0f), (float)(Wc - 1));
    float py = fminf(fmaxf((float)h - mvy * syk, 0.0f), (float)(Hc - 1));
    const int x0 = min((int)floorf(px), Wc - 2);
    const int y0 = min((int)floorf(py), Hc - 2);
    const float wx = px - (float)x0;
    const float wy = py - (float)y0;
    const float w00 = (1.0f - wx) * (1.0f - wy);
    const float w01 = wx * (1.0f - wy);
    const float w10 = (1.0f - wx) * wy;
    const float w11 = wx * wy;
    const size_t o0 = (size_t)y0 * Wc + x0;
    const size_t o1 = o0 + Wc;
    const size_t base_b = (size_t)b * Cc * PLANE;

    #pragma unroll
    for (int cg = 0; cg < Cc; cg += 4) {
        f2 p0[4], p1[4];
        float cu[4];
        #pragma unroll
        for (int j = 0; j < 4; ++j) {
            const size_t cb = base_b + (size_t)(cg + j) * PLANE;
            p0[j] = *(const f2*)(prev + cb + o0);
            p1[j] = *(const f2*)(prev + cb + o1);
            cu[j] = cur[cb + pix];
        }
        #pragma unroll
        for (int j = 0; j < 4; ++j) {
            const size_t cb = base_b + (size_t)(cg + j) * PLANE;
            const float warped = p0[j].x * w00 + p0[j].y * w01
                               + p1[j].x * w10 + p1[j].y * w11;
            out[cb + pix] = ALPHA * warped + (1.0f - ALPHA) * cu[j];
        }
    }
}

extern "C" void kernel_launch(void* const* d_in, const int* in_sizes, int n_in,
                              void* d_out, int out_size, void* d_ws, size_t ws_size,
                              hipStream_t stream) {
    const float* cur  = (const float*)d_in[0];
    const float* prev = (const float*)d_in[1];
    const float* mv   = (const float*)d_in[2];
    float* out = (float*)d_out;

    if (ws_size >= WS_NEED) {
        __half* ws = (__half*)d_ws;
        TemporalEMA_repack_kernel<<<Bc * BLK_PER_B, 256, 0, stream>>>(prev, ws);
        TemporalEMA_73194832658797_kernel<<<NBLK, 256, 0, stream>>>(cur, ws, mv, out);
    } else {
        TemporalEMA_fallback_kernel<<<NBLK, 256, 0, stream>>>(cur, prev, mv, out);
    }
}

// Round 11
// 511.536 us; speedup vs baseline: 1.3912x; 1.0979x over previous
//
#include <hip/hip_runtime.h>
#include <hip/hip_fp16.h>

// TemporalEMA: out = ALPHA * bilinear_warp(prev, mv) + (1-ALPHA) * cur
// R11 = R8 pixel-major f16 ws + two L1-miss levers:
//  (1) 64x8 tile (512 thr): gather footprint 131KB per 64KB useful taps
//      (2.1x amplification) vs 64x4's 117KB/32KB (3.7x) -> L1-miss line
//      traffic x0.56. Measured wall is MSHR x L2-latency bound (~500
//      misses/wave x ~300cy / ~64 slots ~= 494us model vs 418 measured).
//  (2) sched_barrier(0) between the 24 issued loads and consumption so the
//      scheduler can't sink cur-loads into the blend loop (R10: VGPR stayed
//      36, loads serialized).

#define ALPHA 0.85f

constexpr int Bc = 4;
constexpr int Cc = 16;
constexpr int Hc = 1080;
constexpr int Wc = 1920;
constexpr size_t PLANE = (size_t)Hc * Wc;
constexpr size_t WS_NEED = (size_t)Bc * PLANE * Cc * sizeof(__half);  // 265 MB

constexpr int TW = 64;
constexpr int TH = 8;                 // 512-thread block, 8 waves
constexpr int NX = Wc / TW;           // 30
constexpr int NY = Hc / TH;           // 135
constexpr int NBLK = Bc * NY * NX;    // 16200
constexpr int NXCD = 8;
constexpr int CHUNK = NBLK / NXCD;    // 2025 (divisible -> bijective)

constexpr int BLK_PER_B = (int)(PLANE / 256);  // 8100 (repack, 256 thr)

typedef float f2 __attribute__((ext_vector_type(2)));
typedef unsigned int u4 __attribute__((ext_vector_type(4)));

// ---------------- kernel 1: repack prev -> [B,H,W,C16] f16 (R8 form) ----------------
__global__ __launch_bounds__(256) void TemporalEMA_repack_kernel(
    const float* __restrict__ prev, __half* __restrict__ ws)
{
    const int b  = blockIdx.x / BLK_PER_B;
    const int wb = blockIdx.x % BLK_PER_B;
    const size_t pix = (size_t)wb * 256 + threadIdx.x;   // within plane

    const float* src = prev + (size_t)b * Cc * PLANE + pix;
    union { __half h[16]; u4 q[2]; } u;
    #pragma unroll
    for (int c = 0; c < Cc; ++c)
        u.h[c] = __float2half(src[(size_t)c * PLANE]);

    u4* dst = (u4*)(ws + ((size_t)b * PLANE + pix) * Cc);
    __builtin_nontemporal_store(u.q[0], &dst[0]);
    __builtin_nontemporal_store(u.q[1], &dst[1]);
}

// ---------------- kernel 2: gather + blend, 64x8 tile ----------------
__global__ __launch_bounds__(512) void TemporalEMA_73194832658797_kernel(
    const float* __restrict__ cur,
    const __half* __restrict__ wsp,
    const float* __restrict__ mv,
    float* __restrict__ out)
{
    const int bid  = blockIdx.x;
    const int work = (bid % NXCD) * CHUNK + bid / NXCD;   // chunked XCD swizzle

    const int tx  = work % NX;
    const int rem = work / NX;
    const int ty  = rem % NY;
    const int b   = rem / NY;

    const int lw = threadIdx.x & 63;
    const int lh = threadIdx.x >> 6;        // 0..7
    const int w  = tx * TW + lw;
    const int h  = ty * TH + lh;

    const size_t pix = (size_t)h * Wc + w;

    const float mvx = __builtin_nontemporal_load(&mv[((size_t)b * 2 + 0) * PLANE + pix]);
    const float mvy = __builtin_nontemporal_load(&mv[((size_t)b * 2 + 1) * PLANE + pix]);

    const float sxk = (float)(Wc - 1) / (float)Wc;
    const float syk = (float)(Hc - 1) / (float)Hc;
    float px = fminf(fmaxf((float)w - mvx * sxk, 0.0f), (float)(Wc - 1));
    float py = fminf(fmaxf((float)h - mvy * syk, 0.0f), (float)(Hc - 1));

    const int x0 = min((int)floorf(px), Wc - 2);   // weights absorb border clamp
    const int y0 = min((int)floorf(py), Hc - 2);
    const float wx = px - (float)x0;
    const float wy = py - (float)y0;

    const float w00 = (1.0f - wx) * (1.0f - wy);
    const float w01 = wx * (1.0f - wy);
    const float w10 = (1.0f - wx) * wy;
    const float w11 = wx * wy;

    // ---- issue ALL 24 loads, then fence the scheduler ----
    const size_t p00 = ((size_t)b * PLANE + (size_t)y0 * Wc + x0) * Cc;
    const u4* g0 = (const u4*)(wsp + p00);                    // v00|v01
    const u4* g1 = (const u4*)(wsp + p00 + (size_t)Wc * Cc);  // v10|v11

    u4 q[4], r[4];
    #pragma unroll
    for (int j = 0; j < 4; ++j) q[j] = g0[j];
    #pragma unroll
    for (int j = 0; j < 4; ++j) r[j] = g1[j];

    const size_t cb0 = (size_t)b * Cc * PLANE + pix;
    float cu[Cc];
    #pragma unroll
    for (int c = 0; c < Cc; ++c)
        cu[c] = __builtin_nontemporal_load(&cur[cb0 + (size_t)c * PLANE]);

    __builtin_amdgcn_sched_barrier(0);   // nothing crosses: loads stay clustered

    // ---- consume ----
    const __half* t0 = (const __half*)&q[0];   // [32]: v00 ch0..15 | v01 ch0..15
    const __half* t1 = (const __half*)&r[0];   // [32]: v10 ch0..15 | v11 ch0..15

    #pragma unroll
    for (int c = 0; c < Cc; ++c) {
        const float v00 = __half2float(t0[c]);
        const float v01 = __half2float(t0[Cc + c]);
        const float v10 = __half2float(t1[c]);
        const float v11 = __half2float(t1[Cc + c]);
        const float warped = v00 * w00 + v01 * w01 + v10 * w10 + v11 * w11;
        __builtin_nontemporal_store(ALPHA * warped + (1.0f - ALPHA) * cu[c],
                                    &out[cb0 + (size_t)c * PLANE]);
    }
}

// ---------------- fallback: R4 direct f32 gather (if ws too small) ----------------
constexpr int FNX = Wc / 64;          // 30
constexpr int FNY = Hc / 4;           // 270
constexpr int FNBLK = Bc * FNY * FNX; // 32400
constexpr int FCHUNK = FNBLK / NXCD;

__global__ __launch_bounds__(256) void TemporalEMA_fallback_kernel(
    const float* __restrict__ cur,
    const float* __restrict__ prev,
    const float* __restrict__ mv,
    float* __restrict__ out)
{
    const int bid  = blockIdx.x;
    const int work = (bid % NXCD) * FCHUNK + bid / NXCD;
    const int tx  = work % FNX;
    const int rem = work / FNX;
    const int ty  = rem % FNY;
    const int b   = rem / FNY;
    const int lw = threadIdx.x & 63;
    const int lh = threadIdx.x >> 6;
    const int w  = tx * 64 + lw;
    const int h  = ty * 4 + lh;
    const size_t pix = (size_t)h * Wc + w;

    const float mvx = mv[((size_t)b * 2 + 0) * PLANE + pix];
    const float mvy = mv[((size_t)b * 2 + 1) * PLANE + pix];
    const float sxk = (float)(Wc - 1) / (float)Wc;
    const float syk = (float)(Hc - 1) / (float)Hc;
    float px = fminf(fmaxf((float)w - mvx * sxk, 0.0f), (float)(Wc - 1));
    float py = fminf(fmaxf((float)h - mvy * syk, 0.0f), (float)(Hc - 1));
    const int x0 = min((int)floorf(px), Wc - 2);
    const int y0 = min((int)floorf(py), Hc - 2);
    const float wx = px - (float)x0;
    const float wy = py - (float)y0;
    const float w00 = (1.0f - wx) * (1.0f - wy);
    const float w01 = wx * (1.0f - wy);
    const float w10 = (1.0f - wx) * wy;
    const float w11 = wx * wy;
    const size_t o0 = (size_t)y0 * Wc + x0;
    const size_t o1 = o0 + Wc;
    const size_t base_b = (size_t)b * Cc * PLANE;

    #pragma unroll
    for (int cg = 0; cg < Cc; cg += 4) {
        f2 p0[4], p1[4];
        float cu[4];
        #pragma unroll
        for (int j = 0; j < 4; ++j) {
            const size_t cb = base_b + (size_t)(cg + j) * PLANE;
            p0[j] = *(const f2*)(prev + cb + o0);
            p1[j] = *(const f2*)(prev + cb + o1);
            cu[j] = cur[cb + pix];
        }
        #pragma unroll
        for (int j = 0; j < 4; ++j) {
            const size_t cb = base_b + (size_t)(cg + j) * PLANE;
            const float warped = p0[j].x * w00 + p0[j].y * w01
                               + p1[j].x * w10 + p1[j].y * w11;
            out[cb + pix] = ALPHA * warped + (1.0f - ALPHA) * cu[j];
        }
    }
}

extern "C" void kernel_launch(void* const* d_in, const int* in_sizes, int n_in,
                              void* d_out, int out_size, void* d_ws, size_t ws_size,
                              hipStream_t stream) {
    const float* cur  = (const float*)d_in[0];
    const float* prev = (const float*)d_in[1];
    const float* mv   = (const float*)d_in[2];
    float* out = (float*)d_out;

    if (ws_size >= WS_NEED) {
        __half* ws = (__half*)d_ws;
        TemporalEMA_repack_kernel<<<Bc * BLK_PER_B, 256, 0, stream>>>(prev, ws);
        TemporalEMA_73194832658797_kernel<<<NBLK, 512, 0, stream>>>(cur, ws, mv, out);
    } else {
        TemporalEMA_fallback_kernel<<<FNBLK, 256, 0, stream>>>(cur, prev, mv, out);
    }
}

// Round 12
// 479.720 us; speedup vs baseline: 1.4835x; 1.0663x over previous
//
#include <hip/hip_runtime.h>
#include <hip/hip_fp16.h>

// TemporalEMA: out = ALPHA * bilinear_warp(prev, mv) + (1-ALPHA) * cur
// R12 = R11 (64x8 tile, pixel-major f16 ws) + register-residency fix:
// the tap bytes were read through an address-taken union since R8
// ((__half*)&q[0]) -> SROA failure -> serialized loads (VGPR stuck at 36).
// Replace with NAMED ext_vector _Float16x8 values; all element accesses are
// compile-time constant -> pure register code; 24 VMEM loads issue up front
// (sched_barrier(0) fence), __launch_bounds__(512,2) lifts the VGPR cap.

#define ALPHA 0.85f

constexpr int Bc = 4;
constexpr int Cc = 16;
constexpr int Hc = 1080;
constexpr int Wc = 1920;
constexpr size_t PLANE = (size_t)Hc * Wc;
constexpr size_t WS_NEED = (size_t)Bc * PLANE * Cc * sizeof(__half);  // 265 MB

constexpr int TW = 64;
constexpr int TH = 8;                 // 512-thread block, 8 waves
constexpr int NX = Wc / TW;           // 30
constexpr int NY = Hc / TH;           // 135
constexpr int NBLK = Bc * NY * NX;    // 16200
constexpr int NXCD = 8;
constexpr int CHUNK = NBLK / NXCD;    // 2025 (divisible -> bijective)

constexpr int BLK_PER_B = (int)(PLANE / 256);  // 8100 (repack, 256 thr)

typedef float f2 __attribute__((ext_vector_type(2)));
typedef _Float16 h8 __attribute__((ext_vector_type(8)));

// ---------------- kernel 1: repack prev -> [B,H,W,C16] f16 ----------------
__global__ __launch_bounds__(256) void TemporalEMA_repack_kernel(
    const float* __restrict__ prev, __half* __restrict__ ws)
{
    const int b  = blockIdx.x / BLK_PER_B;
    const int wb = blockIdx.x % BLK_PER_B;
    const size_t pix = (size_t)wb * 256 + threadIdx.x;   // within plane

    const float* src = prev + (size_t)b * Cc * PLANE + pix;
    h8 v0, v1;
    #pragma unroll
    for (int c = 0; c < 8; ++c)
        v0[c] = (_Float16)src[(size_t)c * PLANE];
    #pragma unroll
    for (int c = 0; c < 8; ++c)
        v1[c] = (_Float16)src[(size_t)(8 + c) * PLANE];

    h8* dst = (h8*)(ws + ((size_t)b * PLANE + pix) * Cc);
    __builtin_nontemporal_store(v0, &dst[0]);
    __builtin_nontemporal_store(v1, &dst[1]);
}

// ---------------- kernel 2: gather + blend, 64x8 tile, register taps ----------------
__global__ __launch_bounds__(512, 2) void TemporalEMA_73194832658797_kernel(
    const float* __restrict__ cur,
    const __half* __restrict__ wsp,
    const float* __restrict__ mv,
    float* __restrict__ out)
{
    const int bid  = blockIdx.x;
    const int work = (bid % NXCD) * CHUNK + bid / NXCD;   // chunked XCD swizzle

    const int tx  = work % NX;
    const int rem = work / NX;
    const int ty  = rem % NY;
    const int b   = rem / NY;

    const int lw = threadIdx.x & 63;
    const int lh = threadIdx.x >> 6;        // 0..7
    const int w  = tx * TW + lw;
    const int h  = ty * TH + lh;

    const size_t pix = (size_t)h * Wc + w;

    const float mvx = __builtin_nontemporal_load(&mv[((size_t)b * 2 + 0) * PLANE + pix]);
    const float mvy = __builtin_nontemporal_load(&mv[((size_t)b * 2 + 1) * PLANE + pix]);

    const float sxk = (float)(Wc - 1) / (float)Wc;
    const float syk = (float)(Hc - 1) / (float)Hc;
    float px = fminf(fmaxf((float)w - mvx * sxk, 0.0f), (float)(Wc - 1));
    float py = fminf(fmaxf((float)h - mvy * syk, 0.0f), (float)(Hc - 1));

    const int x0 = min((int)floorf(px), Wc - 2);   // weights absorb border clamp
    const int y0 = min((int)floorf(py), Hc - 2);
    const float wx = px - (float)x0;
    const float wy = py - (float)y0;

    const float w00 = (1.0f - wx) * (1.0f - wy);
    const float w01 = wx * (1.0f - wy);
    const float w10 = (1.0f - wx) * wy;
    const float w11 = wx * wy;

    // ---- issue ALL loads into NAMED registers, then fence ----
    const size_t p00 = ((size_t)b * PLANE + (size_t)y0 * Wc + x0) * Cc;
    const h8* g0 = (const h8*)(wsp + p00);                    // v00(ch0-7,8-15), v01(...)
    const h8* g1 = (const h8*)(wsp + p00 + (size_t)Wc * Cc);  // v10, v11

    const h8 a0 = g0[0], a1 = g0[1], a2 = g0[2], a3 = g0[3];
    const h8 b0 = g1[0], b1 = g1[1], b2 = g1[2], b3 = g1[3];

    const size_t cb0 = (size_t)b * Cc * PLANE + pix;
    float cu[Cc];
    #pragma unroll
    for (int c = 0; c < Cc; ++c)
        cu[c] = __builtin_nontemporal_load(&cur[cb0 + (size_t)c * PLANE]);

    __builtin_amdgcn_sched_barrier(0);   // loads stay clustered above

    // ---- consume (all indices compile-time constant -> register code) ----
    #pragma unroll
    for (int c = 0; c < Cc; ++c) {
        const float v00 = (float)(c < 8 ? a0[c & 7] : a1[c & 7]);
        const float v01 = (float)(c < 8 ? a2[c & 7] : a3[c & 7]);
        const float v10 = (float)(c < 8 ? b0[c & 7] : b1[c & 7]);
        const float v11 = (float)(c < 8 ? b2[c & 7] : b3[c & 7]);
        const float warped = v00 * w00 + v01 * w01 + v10 * w10 + v11 * w11;
        __builtin_nontemporal_store(ALPHA * warped + (1.0f - ALPHA) * cu[c],
                                    &out[cb0 + (size_t)c * PLANE]);
    }
}

// ---------------- fallback: R4 direct f32 gather (if ws too small) ----------------
constexpr int FNX = Wc / 64;          // 30
constexpr int FNY = Hc / 4;           // 270
constexpr int FNBLK = Bc * FNY * FNX; // 32400
constexpr int FCHUNK = FNBLK / NXCD;

__global__ __launch_bounds__(256) void TemporalEMA_fallback_kernel(
    const float* __restrict__ cur,
    const float* __restrict__ prev,
    const float* __restrict__ mv,
    float* __restrict__ out)
{
    const int bid  = blockIdx.x;
    const int work = (bid % NXCD) * FCHUNK + bid / NXCD;
    const int tx  = work % FNX;
    const int rem = work / FNX;
    const int ty  = rem % FNY;
    const int b   = rem / FNY;
    const int lw = threadIdx.x & 63;
    const int lh = threadIdx.x >> 6;
    const int w  = tx * 64 + lw;
    const int h  = ty * 4 + lh;
    const size_t pix = (size_t)h * Wc + w;

    const float mvx = mv[((size_t)b * 2 + 0) * PLANE + pix];
    const float mvy = mv[((size_t)b * 2 + 1) * PLANE + pix];
    const float sxk = (float)(Wc - 1) / (float)Wc;
    const float syk = (float)(Hc - 1) / (float)Hc;
    float px = fminf(fmaxf((float)w - mvx * sxk, 0.0f), (float)(Wc - 1));
    float py = fminf(fmaxf((float)h - mvy * syk, 0.0f), (float)(Hc - 1));
    const int x0 = min((int)floorf(px), Wc - 2);
    const int y0 = min((int)floorf(py), Hc - 2);
    const float wx = px - (float)x0;
    const float wy = py - (float)y0;
    const float w00 = (1.0f - wx) * (1.0f - wy);
    const float w01 = wx * (1.0f - wy);
    const float w10 = (1.0f - wx) * wy;
    const float w11 = wx * wy;
    const size_t o0 = (size_t)y0 * Wc + x0;
    const size_t o1 = o0 + Wc;
    const size_t base_b = (size_t)b * Cc * PLANE;

    #pragma unroll
    for (int cg = 0; cg < Cc; cg += 4) {
        f2 p0[4], p1[4];
        float cu[4];
        #pragma unroll
        for (int j = 0; j < 4; ++j) {
            const size_t cb = base_b + (size_t)(cg + j) * PLANE;
            p0[j] = *(const f2*)(prev + cb + o0);
            p1[j] = *(const f2*)(prev + cb + o1);
            cu[j] = cur[cb + pix];
        }
        #pragma unroll
        for (int j = 0; j < 4; ++j) {
            const size_t cb = base_b + (size_t)(cg + j) * PLANE;
            const float warped = p0[j].x * w00 + p0[j].y * w01
                               + p1[j].x * w10 + p1[j].y * w11;
            out[cb + pix] = ALPHA * warped + (1.0f - ALPHA) * cu[j];
        }
    }
}

extern "C" void kernel_launch(void* const* d_in, const int* in_sizes, int n_in,
                              void* d_out, int out_size, void* d_ws, size_t ws_size,
                              hipStream_t stream) {
    const float* cur  = (const float*)d_in[0];
    const float* prev = (const float*)d_in[1];
    const float* mv   = (const float*)d_in[2];
    float* out = (float*)d_out;

    if (ws_size >= WS_NEED) {
        __half* ws = (__half*)d_ws;
        TemporalEMA_repack_kernel<<<Bc * BLK_PER_B, 256, 0, stream>>>(prev, ws);
        TemporalEMA_73194832658797_kernel<<<NBLK, 512, 0, stream>>>(cur, ws, mv, out);
    } else {
        TemporalEMA_fallback_kernel<<<FNBLK, 256, 0, stream>>>(cur, prev, mv, out);
    }
}